// Round 12
// baseline (272.223 us; speedup 1.0000x reference)
//
#include <hip/hip_runtime.h>
#include <math.h>
#include <stdint.h>

#define CDIM 128
#define NTOT 4096
#define LOG2E 1.4426950408889634f

typedef _Float16 f16x8 __attribute__((ext_vector_type(8)));  // 8 fp16 (4 VGPRs)
typedef float floatx4 __attribute__((ext_vector_type(4)));   // MFMA accumulator

static __device__ __forceinline__ floatx4 mfma16(f16x8 a, f16x8 b, floatx4 c) {
    return __builtin_amdgcn_mfma_f32_16x16x32_f16(a, b, c, 0, 0, 0);
}
static __device__ __forceinline__ unsigned short f2h(float f) {
    _Float16 h = (_Float16)f;
    return __builtin_bit_cast(unsigned short, h);
}
static __device__ __forceinline__ float h2f(unsigned short u) {
    return (float)__builtin_bit_cast(_Float16, u);
}
// packed fp32x2 -> fp16x2 (round-toward-zero; P in [0,1], error < 1 ulp fp16)
static __device__ __forceinline__ unsigned int pkrtz(float a, float b) {
    typedef __fp16 hv2 __attribute__((ext_vector_type(2)));   // builtin's return type
    hv2 h = __builtin_amdgcn_cvt_pkrtz(a, b);
    return __builtin_bit_cast(unsigned int, h);
}

// XOR-swizzled LDS addressing (ush units).
// Ks rows: 128 ush, 16 chunks of 8 ush. Vs/Ps rows: 64 ush, 8 chunks.
#define SWZK(row, cc) (((row) << 7) + ((((cc) ^ ((row) & 15))) << 3))
#define SWZV(row, cc) (((row) << 6) + ((((cc) ^ ((row) & 7))) << 3))

// ---------------------------------------------------------------------------
// Fused q/k/v projection, MFMA. x: [4][128][4096] fp32.
// Outputs fp16: qo, ko: [b][n][c]; vo: [b][c][n].
// q is PRE-SCALED by log2(e) (Wq, bq scaled) so attn logits are log2-domain.
// grid (64 n-tiles, 4 batches, 2 o-halves), 256 threads / 4 waves.
// ---------------------------------------------------------------------------
__global__ __launch_bounds__(256) void qkv_proj_kernel(
    const float* __restrict__ x,
    const float* __restrict__ Wq, const float* __restrict__ bq,
    const float* __restrict__ Wk, const float* __restrict__ bk,
    const float* __restrict__ Wv, const float* __restrict__ bv,
    unsigned short* __restrict__ qo, unsigned short* __restrict__ ko,
    unsigned short* __restrict__ vo)
{
    __shared__ __align__(16) unsigned short Xs[64][136];   // [n][c] fp16
    __shared__ __align__(16) unsigned short Ws[64][136];   // [o-half][c] fp16

    const int t = threadIdx.x, b = blockIdx.y, n0 = blockIdx.x * 64;
    const int zo = blockIdx.z * 64;
    const int w = t >> 6, quad = (t >> 4) & 3, l15 = t & 15;

    // stage x tile with transpose-on-store: thread covers 4n x 8c
    {
        const int n = (t & 15) * 4;
        const int c = (t >> 4) * 8;
        float4 xr[8];
        #pragma unroll
        for (int j = 0; j < 8; ++j)
            xr[j] = *(const float4*)&x[((size_t)b * CDIM + c + j) * NTOT + n0 + n];
        #pragma unroll
        for (int k = 0; k < 4; ++k) {
            ushort4 ulo, uhi;
            ulo.x = f2h(((const float*)&xr[0])[k]);
            ulo.y = f2h(((const float*)&xr[1])[k]);
            ulo.z = f2h(((const float*)&xr[2])[k]);
            ulo.w = f2h(((const float*)&xr[3])[k]);
            uhi.x = f2h(((const float*)&xr[4])[k]);
            uhi.y = f2h(((const float*)&xr[5])[k]);
            uhi.z = f2h(((const float*)&xr[6])[k]);
            uhi.w = f2h(((const float*)&xr[7])[k]);
            *(ushort4*)&Xs[n + k][c]     = ulo;
            *(ushort4*)&Xs[n + k][c + 4] = uhi;
        }
    }

    f16x8 xf[4];
    for (int s = 0; s < 3; ++s) {
        const float* W    = (s == 0) ? Wq : (s == 1) ? Wk : Wv;
        const float* bias = (s == 0) ? bq : (s == 1) ? bk : bv;
        const float wscale = (s == 0) ? LOG2E : 1.0f;
        if (s) __syncthreads();   // previous Ws readers done
        {
            int o = t >> 2, ch = (t & 3) * 32;
            #pragma unroll
            for (int i = 0; i < 8; ++i) {
                float4 f4 = *(const float4*)&W[(size_t)(zo + o) * CDIM + ch + i * 4];
                ushort4 u = { f2h(f4.x * wscale), f2h(f4.y * wscale),
                              f2h(f4.z * wscale), f2h(f4.w * wscale) };
                *(ushort4*)&Ws[o][ch + i * 4] = u;
            }
        }
        __syncthreads();          // Ws (and on s==0, Xs) ready
        if (s == 0) {
            #pragma unroll
            for (int f = 0; f < 4; ++f)
                xf[f] = *(const f16x8*)&Xs[w * 16 + l15][f * 32 + quad * 8];
        }

        if (s < 2) {   // q, k: C[o][n], A = W, B = X
            unsigned short* dst = (s == 0) ? qo : ko;
            #pragma unroll
            for (int ot = 0; ot < 4; ++ot) {
                floatx4 acc = (floatx4){0.f, 0.f, 0.f, 0.f};
                #pragma unroll
                for (int f = 0; f < 4; ++f) {
                    f16x8 aW = *(const f16x8*)&Ws[ot * 16 + l15][f * 32 + quad * 8];
                    acc = mfma16(aW, xf[f], acc);
                }
                const int ob = zo + ot * 16 + quad * 4;
                ushort4 u;
                u.x = f2h(acc[0] + wscale * bias[ob + 0]);
                u.y = f2h(acc[1] + wscale * bias[ob + 1]);
                u.z = f2h(acc[2] + wscale * bias[ob + 2]);
                u.w = f2h(acc[3] + wscale * bias[ob + 3]);
                *(ushort4*)&dst[((size_t)b * NTOT + n0 + w * 16 + l15) * CDIM + ob] = u;
            }
        } else {       // v: C'[n][o], A = X, B = W
            #pragma unroll
            for (int ot = 0; ot < 4; ++ot) {
                floatx4 acc = (floatx4){0.f, 0.f, 0.f, 0.f};
                #pragma unroll
                for (int f = 0; f < 4; ++f) {
                    f16x8 bW = *(const f16x8*)&Ws[ot * 16 + l15][f * 32 + quad * 8];
                    acc = mfma16(xf[f], bW, acc);
                }
                const int o = zo + ot * 16 + l15;
                const float bv_ = bias[o];
                ushort4 u;
                u.x = f2h(acc[0] + bv_); u.y = f2h(acc[1] + bv_);
                u.z = f2h(acc[2] + bv_); u.w = f2h(acc[3] + bv_);
                *(ushort4*)&vo[((size_t)b * CDIM + o) * NTOT + n0 + w * 16 + quad * 4] = u;
            }
        }
    }
}

// ---------------------------------------------------------------------------
// Flash attention, split-K(8), KT=64, 4 blocks/CU. Logits in log2 domain.
// q,k: [b][n][128] fp16 (q pre-scaled by log2e); v: [b][128][n] fp16.
// grid (32 q-tiles, 4 batches, 8 key-eighths) = 1024 blocks, 256 thr / 4 waves.
// BQ=128: wave w owns 32 queries (2 n-tiles); 8 iters over 512-key eighth.
// LDS 32 KB (Ks 16 + Vs 16, Ps overlaid on Ks after barrier C) -> 4 blocks/CU
// at VGPR<=128 (launch_bounds(256,4)). Partials self-normalized + stats.
// ---------------------------------------------------------------------------
__global__ __launch_bounds__(256, 4) void attn_kernel(
    const unsigned short* __restrict__ qg,
    const unsigned short* __restrict__ kg,
    const unsigned short* __restrict__ vg,
    unsigned short* __restrict__ Op,
    float* __restrict__ Ms, float* __restrict__ Ls)
{
    __shared__ __align__(16) unsigned short Ks[64 * 128];   // [j][c] 16 KB (becomes Ps after C)
    __shared__ __align__(16) unsigned short Vs[128 * 64];   // [d][j] 16 KB

    const int t = threadIdx.x;
    const int w = t >> 6, quad = (t >> 4) & 3, l15 = t & 15;
    const int b = blockIdx.y;
    const int z = blockIdx.z;
    const int i0 = blockIdx.x * 128;
    const int jbase = z * 512;
    const size_t vbase = (size_t)b * CDIM * NTOT;

    // Q B-fragments direct from global: wave owns queries i0 + w*32 + nt*16 + l15
    f16x8 bQ[2][4];
    #pragma unroll
    for (int nt = 0; nt < 2; ++nt) {
        const size_t qrow = ((size_t)b * NTOT + i0 + w * 32 + nt * 16 + l15) * CDIM;
        #pragma unroll
        for (int f = 0; f < 4; ++f)
            bQ[nt][f] = *(const f16x8*)&qg[qrow + f * 32 + quad * 8];
    }

    floatx4 accO[2][8];   // [nt][dt]
    #pragma unroll
    for (int nt = 0; nt < 2; ++nt)
        #pragma unroll
        for (int dt = 0; dt < 8; ++dt) accO[nt][dt] = (floatx4){0.f, 0.f, 0.f, 0.f};
    float m_run[2] = {-INFINITY, -INFINITY};
    float l_part[2] = {0.f, 0.f};

    for (int iter = 0; iter < 8; ++iter) {
        const int j0 = jbase + iter * 64;
        __syncthreads();   // (A) prev iter's PV reads of Vs/Ps done

        // stage K tile [64 j][128 c] and V tile [128 d][64 j], swizzled
        {
            const size_t kb_ = ((size_t)b * NTOT + j0) * CDIM;
            #pragma unroll
            for (int r = 0; r < 4; ++r) {
                int fk = r * 256 + t;
                int krow = fk >> 4, kcc = fk & 15;
                *(uint4*)&Ks[SWZK(krow, kcc)] =
                    *(const uint4*)&kg[kb_ + (size_t)krow * CDIM + kcc * 8];
                int vrow = fk >> 3, vcc = fk & 7;
                *(uint4*)&Vs[SWZV(vrow, vcc)] =
                    *(const uint4*)&vg[vbase + (size_t)vrow * NTOT + j0 + vcc * 8];
            }
        }
        __syncthreads();   // (B) tiles ready

        // --- T^T[j][i] = K·Q^T : 4 j-tiles x 2 q-tiles (1 aK read -> 2 MFMA) ---
        floatx4 accT[2][4];
        #pragma unroll
        for (int nt = 0; nt < 2; ++nt)
            #pragma unroll
            for (int jt = 0; jt < 4; ++jt) accT[nt][jt] = (floatx4){0.f, 0.f, 0.f, 0.f};
        #pragma unroll
        for (int jt = 0; jt < 4; ++jt)
            #pragma unroll
            for (int f = 0; f < 4; ++f) {
                f16x8 aK = *(const f16x8*)&Ks[SWZK(jt * 16 + l15, f * 4 + quad)];
                accT[0][jt] = mfma16(aK, bQ[0][f], accT[0][jt]);
                accT[1][jt] = mfma16(aK, bQ[1][f], accT[1][jt]);
            }

        // --- online softmax, log2 domain (per-lane; lane = one query) ---
        uint2 pu[2][4];
        #pragma unroll
        for (int nt = 0; nt < 2; ++nt) {
            float tm = accT[nt][0][0];
            #pragma unroll
            for (int jt = 0; jt < 4; ++jt)
                #pragma unroll
                for (int r = 0; r < 4; ++r) tm = fmaxf(tm, accT[nt][jt][r]);
            tm = fmaxf(tm, __shfl_xor(tm, 16));
            tm = fmaxf(tm, __shfl_xor(tm, 32));
            const float m_new = fmaxf(m_run[nt], tm);
            const float alpha = exp2f(m_run[nt] - m_new);   // 0 on first tile
            m_run[nt] = m_new;
            float ps = 0.f;
            #pragma unroll
            for (int jt = 0; jt < 4; ++jt) {
                float p0 = exp2f(accT[nt][jt][0] - m_new);
                float p1 = exp2f(accT[nt][jt][1] - m_new);
                float p2 = exp2f(accT[nt][jt][2] - m_new);
                float p3 = exp2f(accT[nt][jt][3] - m_new);
                ps += (p0 + p1) + (p2 + p3);
                pu[nt][jt].x = pkrtz(p0, p1);
                pu[nt][jt].y = pkrtz(p2, p3);
            }
            l_part[nt] = l_part[nt] * alpha + ps;
            #pragma unroll
            for (int dt = 0; dt < 8; ++dt) {
                accO[nt][dt][0] *= alpha; accO[nt][dt][1] *= alpha;
                accO[nt][dt][2] *= alpha; accO[nt][dt][3] *= alpha;
            }
        }

        __syncthreads();   // (C) all waves' S reads of Ks done -> Ps overlay safe

        // Ps overlay in Ks buffer: wave-private rows prow = w*32 + nt*16 + l15,
        // 64-ush rows, chunk cc = 2*jt + (quad>>1), sub-offset (quad&1)*4 ush.
        #pragma unroll
        for (int nt = 0; nt < 2; ++nt) {
            const int prow = w * 32 + nt * 16 + l15;
            #pragma unroll
            for (int jt = 0; jt < 4; ++jt)
                *(uint2*)&Ks[SWZV(prow, 2 * jt + (quad >> 1)) + (quad & 1) * 4] =
                    pu[nt][jt];
        }

        // --- O^T += V·P^T (wave-private P; 1 aV read -> 2 MFMA) ---
        f16x8 bP[2][2];
        #pragma unroll
        for (int nt = 0; nt < 2; ++nt) {
            const int prow = w * 32 + nt * 16 + l15;
            #pragma unroll
            for (int kb = 0; kb < 2; ++kb)
                bP[nt][kb] = *(const f16x8*)&Ks[SWZV(prow, kb * 4 + quad)];
        }
        #pragma unroll
        for (int dt = 0; dt < 8; ++dt)
            #pragma unroll
            for (int kb = 0; kb < 2; ++kb) {
                f16x8 aV = *(const f16x8*)&Vs[SWZV(dt * 16 + l15, kb * 4 + quad)];
                accO[0][dt] = mfma16(aV, bP[0][kb], accO[0][dt]);
                accO[1][dt] = mfma16(aV, bP[1][kb], accO[1][dt]);
            }
    }

    // final l over quads; store normalized partials + stats (m in log2 units)
    #pragma unroll
    for (int nt = 0; nt < 2; ++nt) {
        float lf = l_part[nt];
        lf += __shfl_xor(lf, 16);
        lf += __shfl_xor(lf, 32);
        const float inv = 1.0f / lf;
        const size_t orow =
            (((size_t)z * 4 + b) * NTOT + i0 + w * 32 + nt * 16 + l15) * CDIM;
        #pragma unroll
        for (int dt = 0; dt < 8; ++dt) {
            ushort4 u;
            u.x = f2h(accO[nt][dt][0] * inv); u.y = f2h(accO[nt][dt][1] * inv);
            u.z = f2h(accO[nt][dt][2] * inv); u.w = f2h(accO[nt][dt][3] * inv);
            *(ushort4*)&Op[orow + dt * 16 + quad * 4] = u;
        }
        if (quad == 0) {
            const int idx = (z * 4 + b) * NTOT + i0 + w * 32 + nt * 16 + l15;
            Ms[idx] = m_run[nt];
            Ls[idx] = lf;
        }
    }
}

// ---------------------------------------------------------------------------
// Output projection + residual with FUSED 8-way split-K combine.
// Op: [8][b][n][128] fp16 partials (self-normalized), Ms/Ls: [8][b*n] (log2).
// out[b][o][n] = Wo·(merge(Op))^T + bo + x. grid (64, 4, 2 o-halves).
// ---------------------------------------------------------------------------
__global__ __launch_bounds__(256) void out_proj_kernel(
    const unsigned short* __restrict__ Op,
    const float* __restrict__ Ms, const float* __restrict__ Ls,
    const float* __restrict__ Wo, const float* __restrict__ bo,
    const float* __restrict__ x, float* __restrict__ out)
{
    __shared__ __align__(16) unsigned short As[64][136];  // [n][c] merged
    __shared__ __align__(16) unsigned short Ws[64][136];  // [o-half][c]

    const int t = threadIdx.x, b = blockIdx.y, n0 = blockIdx.x * 64;
    const int zo = blockIdx.z * 64;
    const int w = t >> 6, quad = (t >> 4) & 3, l15 = t & 15;

    const size_t PER_OP = (size_t)NTOT * 4 * CDIM;   // elems per key-eighth

    #pragma unroll
    for (int r = 0; r < 4; ++r) {   // stage merged ao tile
        int flat = r * 256 + t;
        int row = flat >> 4, c16 = (flat & 15) * 8;
        const int bn = b * NTOT + n0 + row;
        float mz[8], wz[8];
        float M = -INFINITY;
        #pragma unroll
        for (int zi = 0; zi < 8; ++zi) { mz[zi] = Ms[bn + zi * 16384]; M = fmaxf(M, mz[zi]); }
        float wsum = 0.f;
        #pragma unroll
        for (int zi = 0; zi < 8; ++zi) {
            wz[zi] = Ls[bn + zi * 16384] * exp2f(mz[zi] - M);
            wsum += wz[zi];
        }
        const float inv = 1.0f / wsum;

        float sacc[8] = {0.f, 0.f, 0.f, 0.f, 0.f, 0.f, 0.f, 0.f};
        const size_t base = (size_t)bn * CDIM + c16;
        #pragma unroll
        for (int zi = 0; zi < 8; ++zi) {
            uint4 a = *(const uint4*)&Op[zi * PER_OP + base];
            const unsigned short* pa = (const unsigned short*)&a;
            #pragma unroll
            for (int j = 0; j < 8; ++j) sacc[j] += wz[zi] * h2f(pa[j]);
        }
        unsigned short mv[8];
        #pragma unroll
        for (int j = 0; j < 8; ++j) mv[j] = f2h(sacc[j] * inv);
        *(uint4*)&As[row][c16] = *(const uint4*)mv;
    }
    {
        int o = t >> 2, ch = (t & 3) * 32;
        #pragma unroll
        for (int i = 0; i < 8; ++i) {
            float4 f4 = *(const float4*)&Wo[(size_t)(zo + o) * CDIM + ch + i * 4];
            ushort4 u = { f2h(f4.x), f2h(f4.y), f2h(f4.z), f2h(f4.w) };
            *(ushort4*)&Ws[o][ch + i * 4] = u;
        }
    }
    __syncthreads();

    f16x8 bA[4];
    #pragma unroll
    for (int f = 0; f < 4; ++f)
        bA[f] = *(const f16x8*)&As[w * 16 + l15][f * 32 + quad * 8];

    #pragma unroll
    for (int ot = 0; ot < 4; ++ot) {
        floatx4 acc = (floatx4){0.f, 0.f, 0.f, 0.f};
        #pragma unroll
        for (int f = 0; f < 4; ++f) {
            f16x8 aW = *(const f16x8*)&Ws[ot * 16 + l15][f * 32 + quad * 8];
            acc = mfma16(aW, bA[f], acc);
        }
        const int ob = zo + ot * 16 + quad * 4;
        #pragma unroll
        for (int r = 0; r < 4; ++r) {
            size_t idx = ((size_t)b * CDIM + ob + r) * NTOT + n0 + w * 16 + l15;
            out[idx] = acc[r] + bo[ob + r] + x[idx];
        }
    }
}

// ---------------------------------------------------------------------------
extern "C" void kernel_launch(void* const* d_in, const int* in_sizes, int n_in,
                              void* d_out, int out_size, void* d_ws, size_t ws_size,
                              hipStream_t stream)
{
    const float* x  = (const float*)d_in[0];
    const float* Wq = (const float*)d_in[1];
    const float* bq = (const float*)d_in[2];
    const float* Wk = (const float*)d_in[3];
    const float* bk = (const float*)d_in[4];
    const float* Wv = (const float*)d_in[5];
    const float* bv = (const float*)d_in[6];
    const float* Wo = (const float*)d_in[7];
    const float* bo = (const float*)d_in[8];
    float* out = (float*)d_out;

    const size_t PER = (size_t)4 * CDIM * NTOT;   // 2,097,152 elements
    unsigned short* q_ws  = (unsigned short*)d_ws;
    unsigned short* k_ws  = q_ws + PER;
    unsigned short* v_ws  = k_ws + PER;
    unsigned short* op_ws = v_ws + PER;           // fp16 [8][b][n][c] partials (33.6 MB)
    float*          ms_ws = (float*)(op_ws + 8 * PER);   // [8][b*n]
    float*          ls_ws = ms_ws + 8 * 16384;

    qkv_proj_kernel<<<dim3(64, 4, 2), dim3(256), 0, stream>>>(
        x, Wq, bq, Wk, bk, Wv, bv, q_ws, k_ws, v_ws);
    attn_kernel<<<dim3(32, 4, 8), dim3(256), 0, stream>>>(
        q_ws, k_ws, v_ws, op_ws, ms_ws, ls_ws);
    out_proj_kernel<<<dim3(64, 4, 2), dim3(256), 0, stream>>>(
        op_ws, ms_ws, ls_ws, Wo, bo, x, out);
}